// Round 15
// baseline (319.122 us; speedup 1.0000x reference)
//
#include <hip/hip_runtime.h>
#include <hip/hip_bf16.h>
#include <math.h>

#define B_    4
#define NTOK  1024
#define CH    512
#define NH    8
#define DH    64
#define BH    32          // B_*NH
#define SCALE 0.125f      // Dh^-0.5

typedef unsigned short u16;
typedef unsigned char  u8;
typedef unsigned int   u32;
typedef short short8 __attribute__((ext_vector_type(8)));
typedef float f32x4  __attribute__((ext_vector_type(4)));
typedef float f32x2  __attribute__((ext_vector_type(2)));

#define MFMA16 __builtin_amdgcn_mfma_f32_16x16x32_bf16
#define MFMA8  __builtin_amdgcn_mfma_f32_16x16x32_fp8_fp8

__device__ __forceinline__ float b2f(u16 u) {
  union { u32 i; float f; } c; c.i = ((u32)u) << 16; return c.f;
}
__device__ __forceinline__ u16 f2b(float f) {     // round-to-nearest-even
  union { float f; u32 i; } c; c.f = f; u32 x = c.i;
  return (u16)((x + 0x7FFFu + ((x >> 16) & 1u)) >> 16);
}
__device__ __forceinline__ u8 f2fp8(float v) {
  return (u8)((u32)__builtin_amdgcn_cvt_pk_fp8_f32(v, v, 0, false) & 0xFF);
}
// pack 4 fp32 -> 4 fp8e4m3 bytes
__device__ __forceinline__ u32 pk_fp8x4(float a, float b, float c, float d) {
  u32 p = (u32)__builtin_amdgcn_cvt_pk_fp8_f32(a, b, 0, false);
  p = (u32)__builtin_amdgcn_cvt_pk_fp8_f32(c, d, (int)p, true);
  return p;
}

// async global->LDS, 16B per lane; lds addr must be linear in lane (base + lane*16)
__device__ __forceinline__ void gload16(const void* g, void* l) {
  __builtin_amdgcn_global_load_lds(
      (const __attribute__((address_space(1))) void*)g,
      (__attribute__((address_space(3))) void*)l, 16, 0, 0);
}

// ---- swizzled staging: LDS tile is [R][64B rows]. 16B slot s' holds
// global slot s'^((row>>1)&3)  ->  ds_read of (row, lg) hits 2-way max conflict.
template<int NB, int NT>
__device__ __forceinline__ void stage(const char* g, size_t gstride, char* lds) {
  #pragma unroll
  for (int off = 0; off < NB; off += NT * 16) {
    int o = off + threadIdx.x * 16;
    int row = o >> 6, slot = (o >> 4) & 3;
    gload16(g + (size_t)row * gstride + ((slot ^ ((row >> 1) & 3)) << 4), lds + o);
  }
}
__device__ __forceinline__ short8 rfrag(const char* lds, int row, int lg) {
  return *(const short8*)(lds + row * 64 + ((lg ^ ((row >> 1) & 3)) << 4));
}
// fp8 frag: row covers K=64 (two MFMA K-blocks); 8B frag at (kk, lg)
__device__ __forceinline__ long rfrag8(const u8* lds, int row, int kk, int lg) {
  return *(const long*)&lds[row * 64 + ((((kk << 1) + (lg >> 1)) ^ ((row >> 1) & 3)) << 4) + ((lg & 1) << 3)];
}

// ---------------- wave reduction helpers (64 lanes, no LDS) ----------------
__device__ __forceinline__ float wave_sum(float v) {
  #pragma unroll
  for (int o = 32; o; o >>= 1) v += __shfl_xor(v, o);
  return v;
}
__device__ __forceinline__ float wave_max(float v) {
  #pragma unroll
  for (int o = 32; o; o >>= 1) v = fmaxf(v, __shfl_xor(v, o));
  return v;
}

// ---------------- cast fp32 -> bf16, 8 elems/thread ----------------
__global__ __launch_bounds__(256) void k_cast(const float* __restrict__ a, u16* __restrict__ o, int n8) {
  int i = blockIdx.x * 256 + threadIdx.x;
  if (i >= n8) return;
  float4 v0 = ((const float4*)a)[i * 2], v1 = ((const float4*)a)[i * 2 + 1];
  ushort4 r0 = {f2b(v0.x), f2b(v0.y), f2b(v0.z), f2b(v0.w)};
  ushort4 r1 = {f2b(v1.x), f2b(v1.y), f2b(v1.z), f2b(v1.w)};
  ((ushort4*)o)[i * 2] = r0; ((ushort4*)o)[i * 2 + 1] = r1;
}

// ---------------- K1: qkv GEMM (bf16 MFMA): [4096x1536] = xb @ wb^T, scatter q/k/vT ----------------
__global__ __launch_bounds__(256) void k_qkv_m(const u16* __restrict__ xb, const u16* __restrict__ wb,
                                               u16* __restrict__ q, u16* __restrict__ kk,
                                               u16* __restrict__ vT) {
  __shared__ u16 Abuf[128 * 32], Bbuf[128 * 32];
  const int tid = threadIdx.x, w = tid >> 6, l = tid & 63;
  const int wr = w >> 1, wc = w & 1, lr = l & 15, lg = l >> 4;
  const int i0 = blockIdx.x * 128, j0 = blockIdx.y * 128;
  const char* Ax = (const char*)xb + (size_t)i0 * 1024;
  const char* Bx = (const char*)wb + (size_t)j0 * 1024;
  f32x4 acc[4][4] = {};
  for (int k0 = 0; k0 < CH; k0 += 32) {
    stage<8192, 256>(Ax + k0 * 2, 1024, (char*)Abuf);
    stage<8192, 256>(Bx + k0 * 2, 1024, (char*)Bbuf);
    __syncthreads();
    short8 a[4], b[4];
    #pragma unroll
    for (int m = 0; m < 4; ++m) a[m] = rfrag((const char*)Abuf, wr * 64 + m * 16 + lr, lg);
    #pragma unroll
    for (int n = 0; n < 4; ++n) b[n] = rfrag((const char*)Bbuf, wc * 64 + n * 16 + lr, lg);
    #pragma unroll
    for (int m = 0; m < 4; ++m)
      #pragma unroll
      for (int n = 0; n < 4; ++n)
        acc[m][n] = MFMA16(a[m], b[n], acc[m][n], 0, 0, 0);
    __syncthreads();
  }
  const int sec = j0 >> 9;          // 0=q 1=k 2=v (tile never crosses a 512 boundary)
  const int b0 = i0 >> 10;          // batch (tile never crosses a 1024 boundary)
  #pragma unroll
  for (int m = 0; m < 4; ++m) {
    #pragma unroll
    for (int n = 0; n < 4; ++n) {
      int gi0 = i0 + wr * 64 + m * 16 + lg * 4;
      int gj  = j0 + wc * 64 + n * 16 + lr;
      int h = (gj >> 6) & 7, d = gj & 63, z = b0 * 8 + h;
      if (sec == 2) {
        size_t base = ((size_t)z * 64 + d) * 1024;
        #pragma unroll
        for (int r = 0; r < 4; ++r) vT[base + ((gi0 + r) & 1023)] = f2b(acc[m][n][r]);
      } else {
        u16* dst = sec ? kk : q;
        #pragma unroll
        for (int r = 0; r < 4; ++r)
          dst[((size_t)z * 1024 + ((gi0 + r) & 1023)) * 64 + d] = f2b(acc[m][n][r]);
      }
    }
  }
}

// ---------------- K2: E = SCALE * q @ k^T per head; rowsum -> S; fp8 copy E8 ----------------
__global__ __launch_bounds__(256) void k_qk_m(const u16* __restrict__ q, const u16* __restrict__ kk,
                                              u16* __restrict__ E, float* __restrict__ S,
                                              u8* __restrict__ E8) {
  __shared__ u16 Abuf[128 * 32], Bbuf[128 * 32];
  const int z = blockIdx.z;
  const int tid = threadIdx.x, w = tid >> 6, l = tid & 63;
  const int wr = w >> 1, wc = w & 1, lr = l & 15, lg = l >> 4;
  const int i0 = blockIdx.x * 128, j0 = blockIdx.y * 128;
  const char* Ax = (const char*)(q  + (size_t)z * NTOK * DH) + (size_t)i0 * 128;
  const char* Bx = (const char*)(kk + (size_t)z * NTOK * DH) + (size_t)j0 * 128;
  u16* Eh = E + (size_t)z * NTOK * NTOK;
  u8* E8h = E8 ? E8 + (size_t)z * NTOK * NTOK : (u8*)0;
  f32x4 acc[4][4] = {};
  for (int k0 = 0; k0 < DH; k0 += 32) {
    stage<8192, 256>(Ax + k0 * 2, 128, (char*)Abuf);
    stage<8192, 256>(Bx + k0 * 2, 128, (char*)Bbuf);
    __syncthreads();
    short8 a[4], b[4];
    #pragma unroll
    for (int m = 0; m < 4; ++m) a[m] = rfrag((const char*)Abuf, wr * 64 + m * 16 + lr, lg);
    #pragma unroll
    for (int n = 0; n < 4; ++n) b[n] = rfrag((const char*)Bbuf, wc * 64 + n * 16 + lr, lg);
    #pragma unroll
    for (int m = 0; m < 4; ++m)
      #pragma unroll
      for (int n = 0; n < 4; ++n)
        acc[m][n] = MFMA16(a[m], b[n], acc[m][n], 0, 0, 0);
    __syncthreads();
  }
  #pragma unroll
  for (int m = 0; m < 4; ++m) {
    #pragma unroll
    for (int n = 0; n < 4; ++n) {
      int gi0 = i0 + wr * 64 + m * 16 + lg * 4;
      int gj  = j0 + wc * 64 + n * 16 + lr;
      #pragma unroll
      for (int r = 0; r < 4; ++r) {
        float v = SCALE * acc[m][n][r];
        Eh[(size_t)(gi0 + r) * NTOK + gj] = f2b(v);
        if (E8h) E8h[(size_t)(gi0 + r) * NTOK + gj] = f2fp8(v);
      }
    }
  }
  // rowsum partials: this wave's 64-col slice; reduce over lr (16-lane group), atomic per row
  #pragma unroll
  for (int m = 0; m < 4; ++m) {
    #pragma unroll
    for (int r = 0; r < 4; ++r) {
      float ps = SCALE * (acc[m][0][r] + acc[m][1][r] + acc[m][2][r] + acc[m][3][r]);
      #pragma unroll
      for (int o = 8; o; o >>= 1) ps += __shfl_xor(ps, o);
      if (lr == 0)
        atomicAdd(&S[(size_t)z * NTOK + i0 + wr * 64 + m * 16 + lg * 4 + r], ps);
    }
  }
}

// ---------------- K4a: corr from fp8 E8 — 512 threads (8 waves, 4x2), BK=64, single-drain ----------------
__global__ __launch_bounds__(512) void k_corr8(const u8* __restrict__ E8, u8* __restrict__ Cr,
                                               const float* __restrict__ S, int first) {
  const int p = blockIdx.x;                 // 0..1151
  const int seq = p >> 3;                   // XCD head-grouping
  const int z = (p & 7) + 8 * (seq / 36);
  int t = seq % 36;
  int ti = 0;
  while (t >= 8 - ti) { t -= 8 - ti; ++ti; }
  const int tj = ti + t;
  const u8* Eh = E8 + (size_t)z * NTOK * NTOK;
  u8* Ch = Cr + (size_t)z * NTOK * NTOK;
  const int i0 = ti * 128, j0 = tj * 128;

  __shared__ u8 A8[2][8192], B8[2][8192];   // 32 KB total, [128 rows][64B = K-64 fp8]
  const int tid = threadIdx.x, w = tid >> 6, l = tid & 63;
  const int wr = w >> 1, wc = w & 1, lr = l & 15, lg = l >> 4;   // 4x2 wave grid
  const char* Ax = (const char*)Eh + (size_t)i0 * 1024;
  const char* Bx = (const char*)Eh + (size_t)j0 * 1024;
  f32x4 acc[2][4] = {};                     // per-wave 32x64

  stage<8192, 512>(Ax, 1024, (char*)A8[0]);
  stage<8192, 512>(Bx, 1024, (char*)B8[0]);
  int cur = 0;
  for (int k0 = 0; k0 < NTOK; k0 += 64) {
    asm volatile("s_waitcnt vmcnt(0)" ::: "memory");
    __builtin_amdgcn_s_barrier();
    asm volatile("" ::: "memory");
    long a[2][2], b[2][4];
    #pragma unroll
    for (int kk = 0; kk < 2; ++kk) {
      #pragma unroll
      for (int m = 0; m < 2; ++m) a[kk][m] = rfrag8(A8[cur], wr * 32 + m * 16 + lr, kk, lg);
      #pragma unroll
      for (int n = 0; n < 4; ++n) b[kk][n] = rfrag8(B8[cur], wc * 64 + n * 16 + lr, kk, lg);
    }
    if (k0 + 64 < NTOK) {
      stage<8192, 512>(Ax + k0 + 64, 1024, (char*)A8[cur ^ 1]);
      stage<8192, 512>(Bx + k0 + 64, 1024, (char*)B8[cur ^ 1]);
    }
    #pragma unroll
    for (int kk = 0; kk < 2; ++kk)
      #pragma unroll
      for (int m = 0; m < 2; ++m)
        #pragma unroll
        for (int n = 0; n < 4; ++n)
          acc[m][n] = MFMA8(a[kk][m], b[kk][n], acc[m][n], 0, 0, 0);
    asm volatile("" ::: "memory");
    __builtin_amdgcn_s_barrier();
    cur ^= 1;
  }

  const float c2 = 0.19f / 1024.0f;
  #pragma unroll
  for (int m = 0; m < 2; ++m) {
    #pragma unroll
    for (int n = 0; n < 4; ++n) {
      const int gi0 = i0 + wr * 32 + m * 16 + lg * 4;
      const int gj  = j0 + wc * 64 + n * 16 + lr;
      float v[4];
      if (first) {
        float sj = S[(size_t)z * NTOK + gj];
        #pragma unroll
        for (int r = 0; r < 4; ++r)
          v[r] = 0.81f * acc[m][n][r] + c2 * S[(size_t)z * NTOK + gi0 + r] * sj;
      } else {
        #pragma unroll
        for (int r = 0; r < 4; ++r) v[r] = acc[m][n][r];
      }
      #pragma unroll
      for (int r = 0; r < 4; ++r) v[r] *= 0.125f;          // 1/8 range guard
      u32 mp = pk_fp8x4(v[0], v[1], v[2], v[3]);
      #pragma unroll
      for (int r = 0; r < 4; ++r)
        Ch[(size_t)(gi0 + r) * NTOK + gj] = (u8)((mp >> (8 * r)) & 0xFF);
      if (ti != tj) {
        *(u32*)&Ch[(size_t)gj * NTOK + gi0] = mp;
      }
    }
  }
}

// ---------------- K4b: corr from bf16 E (fallback path, 256 threads) ----------------
__global__ __launch_bounds__(256) void k_corr(const u16* __restrict__ E, u8* __restrict__ Cr,
                                              const float* __restrict__ S, int first) {
  const int p = blockIdx.x;
  const int seq = p >> 3;
  const int z = (p & 7) + 8 * (seq / 36);
  int t = seq % 36;
  int ti = 0;
  while (t >= 8 - ti) { t -= 8 - ti; ++ti; }
  const int tj = ti + t;
  const u16* Eh = E + (size_t)z * NTOK * NTOK;
  u8* Ch = Cr + (size_t)z * NTOK * NTOK;
  const int i0 = ti * 128, j0 = tj * 128;

  __shared__ u16 Abuf[2][4096], Bbuf[2][4096];
  const int tid = threadIdx.x, w = tid >> 6, l = tid & 63;
  const int wr = w >> 1, wc = w & 1, lr = l & 15, lg = l >> 4;
  const char* Ax = (const char*)Eh + (size_t)i0 * 2048;
  const char* Bx = (const char*)Eh + (size_t)j0 * 2048;
  f32x4 acc[4][4] = {};

  stage<8192, 256>(Ax, 2048, (char*)Abuf[0]);
  stage<8192, 256>(Bx, 2048, (char*)Bbuf[0]);
  __syncthreads();
  int cur = 0;
  for (int k0 = 0; k0 < NTOK; k0 += 32) {
    if (k0 + 32 < NTOK) {
      stage<8192, 256>(Ax + (k0 + 32) * 2, 2048, (char*)Abuf[cur ^ 1]);
      stage<8192, 256>(Bx + (k0 + 32) * 2, 2048, (char*)Bbuf[cur ^ 1]);
    }
    short8 a[4], b[4];
    #pragma unroll
    for (int m = 0; m < 4; ++m) a[m] = rfrag((const char*)Abuf[cur], wr * 64 + m * 16 + lr, lg);
    #pragma unroll
    for (int n = 0; n < 4; ++n) b[n] = rfrag((const char*)Bbuf[cur], wc * 64 + n * 16 + lr, lg);
    #pragma unroll
    for (int m = 0; m < 4; ++m)
      #pragma unroll
      for (int n = 0; n < 4; ++n)
        acc[m][n] = MFMA16(a[m], b[n], acc[m][n], 0, 0, 0);
    __syncthreads();
    cur ^= 1;
  }

  const float c2 = 0.19f / 1024.0f;
  #pragma unroll
  for (int m = 0; m < 4; ++m) {
    #pragma unroll
    for (int n = 0; n < 4; ++n) {
      const int gi0 = i0 + wr * 64 + m * 16 + lg * 4;
      const int gj  = j0 + wc * 64 + n * 16 + lr;
      float v[4];
      if (first) {
        float sj = S[(size_t)z * NTOK + gj];
        #pragma unroll
        for (int r = 0; r < 4; ++r)
          v[r] = 0.81f * acc[m][n][r] + c2 * S[(size_t)z * NTOK + gi0 + r] * sj;
      } else {
        #pragma unroll
        for (int r = 0; r < 4; ++r) v[r] = acc[m][n][r];
      }
      #pragma unroll
      for (int r = 0; r < 4; ++r) v[r] *= 0.125f;
      u32 mp = pk_fp8x4(v[0], v[1], v[2], v[3]);
      #pragma unroll
      for (int r = 0; r < 4; ++r)
        Ch[(size_t)(gi0 + r) * NTOK + gj] = (u8)((mp >> (8 * r)) & 0xFF);
      if (ti != tj) {
        *(u32*)&Ch[(size_t)gj * NTOK + gi0] = mp;
      }
    }
  }
}

// ---------------- K5: E-update, wave-per-row (no LDS/barriers); optional E8 re-emit ----------------
__global__ __launch_bounds__(256) void k_fix(u16* __restrict__ E, const u8* __restrict__ Cr,
                                             const float* __restrict__ S, u8* __restrict__ E8,
                                             int fb, int last) {
  const int row = blockIdx.x * 4 + (threadIdx.x >> 6);
  const int l = threadIdx.x & 63;
  const size_t roff = (size_t)row * NTOK;

  uint4 cw = ((const uint4*)(Cr + roff))[l];          // 16 fp8
  float c[16];
  #pragma unroll
  for (int i = 0; i < 4; ++i) {
    u32 wbits = ((const u32*)&cw)[i];
    f32x2 lo = __builtin_amdgcn_cvt_pk_f32_fp8(wbits, false);
    f32x2 hi = __builtin_amdgcn_cvt_pk_f32_fp8(wbits, true);
    c[i * 4 + 0] = lo[0]; c[i * 4 + 1] = lo[1]; c[i * 4 + 2] = hi[0]; c[i * 4 + 3] = hi[1];
  }
  short8 ev0 = ((const short8*)(E + roff))[l * 2];
  short8 ev1 = ((const short8*)(E + roff))[l * 2 + 1];
  float e[16];
  #pragma unroll
  for (int i = 0; i < 8; ++i) { e[i] = b2f((u16)ev0[i]); e[8 + i] = b2f((u16)ev1[i]); }

  float ss = 0.f;
  #pragma unroll
  for (int i = 0; i < 16; ++i) ss += c[i] * c[i];
  float norm8 = sqrtf(wave_sum(ss));                  // = ||corr||/8
  float sc = 0.4f / (8.0f * norm8 + 1e-8f);           // 0.05*8

  if (fb) {
    float mm = 0.1f * S[row] * (1.0f / 1024.0f);
    #pragma unroll
    for (int i = 0; i < 16; ++i) e[i] = 0.9f * e[i] + mm;
  }
  #pragma unroll
  for (int i = 0; i < 16; ++i) e[i] += sc * c[i];

  if (!last) {
    float s = 0.f;
    #pragma unroll
    for (int i = 0; i < 16; ++i) s += e[i];
    float m = wave_sum(s) * (1.0f / 1024.0f);
    #pragma unroll
    for (int i = 0; i < 16; ++i) e[i] = 0.9f * e[i] + 0.1f * m;
    if (E8) {
      uint4 p;
      #pragma unroll
      for (int i = 0; i < 4; ++i)
        ((u32*)&p)[i] = pk_fp8x4(e[i * 4], e[i * 4 + 1], e[i * 4 + 2], e[i * 4 + 3]);
      ((uint4*)(E8 + roff))[l] = p;
    }
  } else {
    float mx = e[0];
    #pragma unroll
    for (int i = 1; i < 16; ++i) mx = fmaxf(mx, e[i]);
    mx = wave_max(mx);
    float s = 0.f;
    #pragma unroll
    for (int i = 0; i < 16; ++i) { e[i] = __expf(e[i] - mx); s += e[i]; }
    float inv = 1.0f / wave_sum(s);
    #pragma unroll
    for (int i = 0; i < 16; ++i) e[i] *= inv;
  }
  #pragma unroll
  for (int i = 0; i < 8; ++i) { ev0[i] = (short)f2b(e[i]); ev1[i] = (short)f2b(e[8 + i]); }
  ((short8*)(E + roff))[l * 2] = ev0;
  ((short8*)(E + roff))[l * 2 + 1] = ev1;
}

// ---------------- K6: Ob[4096x512] = P @ v per head (bf16 MFMA), N-tile=64 ----------------
__global__ __launch_bounds__(256) void k_pv_m(const u16* __restrict__ E, const u16* __restrict__ vT,
                                              u16* __restrict__ Ob) {
  __shared__ u16 Abuf[128 * 32], Bbuf[64 * 32];
  const int z = blockIdx.y, b0 = z >> 3, h = z & 7;
  const int tid = threadIdx.x, w = tid >> 6, l = tid & 63;
  const int wr = w >> 1, wc = w & 1, lr = l & 15, lg = l >> 4;
  const int i0 = blockIdx.x * 128;
  const char* Ax = (const char*)(E  + (size_t)z * NTOK * NTOK) + (size_t)i0 * 2048;
  const char* Bx = (const char*)(vT + (size_t)z * DH * NTOK);
  f32x4 acc[4][2] = {};
  for (int k0 = 0; k0 < NTOK; k0 += 32) {
    stage<8192, 256>(Ax + k0 * 2, 2048, (char*)Abuf);
    stage<4096, 256>(Bx + k0 * 2, 2048, (char*)Bbuf);
    __syncthreads();
    short8 a[4], b[2];
    #pragma unroll
    for (int m = 0; m < 4; ++m) a[m] = rfrag((const char*)Abuf, wr * 64 + m * 16 + lr, lg);
    #pragma unroll
    for (int n = 0; n < 2; ++n) b[n] = rfrag((const char*)Bbuf, wc * 32 + n * 16 + lr, lg);
    #pragma unroll
    for (int m = 0; m < 4; ++m)
      #pragma unroll
      for (int n = 0; n < 2; ++n)
        acc[m][n] = MFMA16(a[m], b[n], acc[m][n], 0, 0, 0);
    __syncthreads();
  }
  #pragma unroll
  for (int m = 0; m < 4; ++m) {
    #pragma unroll
    for (int n = 0; n < 2; ++n) {
      int gi0 = i0 + wr * 64 + m * 16 + lg * 4;
      int d   = wc * 32 + n * 16 + lr;
      #pragma unroll
      for (int r = 0; r < 4; ++r)
        Ob[((size_t)b0 * 1024 + gi0 + r) * 512 + h * 64 + d] = f2b(acc[m][n][r]);
    }
  }
}

// ---------------- K7: out[4096x512] = Ob @ wprojb^T + bias (bf16 MFMA, fp32 out) ----------------
__global__ __launch_bounds__(256) void k_proj_m(const u16* __restrict__ Ob, const u16* __restrict__ wb,
                                                const float* __restrict__ bias, float* __restrict__ out) {
  __shared__ u16 Abuf[128 * 32], Bbuf[128 * 32];
  const int tid = threadIdx.x, w = tid >> 6, l = tid & 63;
  const int wr = w >> 1, wc = w & 1, lr = l & 15, lg = l >> 4;
  const int i0 = blockIdx.x * 128, j0 = blockIdx.y * 128;
  const char* Ax = (const char*)Ob + (size_t)i0 * 1024;
  const char* Bx = (const char*)wb + (size_t)j0 * 1024;
  f32x4 acc[4][4] = {};
  for (int k0 = 0; k0 < CH; k0 += 32) {
    stage<8192, 256>(Ax + k0 * 2, 1024, (char*)Abuf);
    stage<8192, 256>(Bx + k0 * 2, 1024, (char*)Bbuf);
    __syncthreads();
    short8 a[4], b[4];
    #pragma unroll
    for (int m = 0; m < 4; ++m) a[m] = rfrag((const char*)Abuf, wr * 64 + m * 16 + lr, lg);
    #pragma unroll
    for (int n = 0; n < 4; ++n) b[n] = rfrag((const char*)Bbuf, wc * 64 + n * 16 + lr, lg);
    #pragma unroll
    for (int m = 0; m < 4; ++m)
      #pragma unroll
      for (int n = 0; n < 4; ++n)
        acc[m][n] = MFMA16(a[m], b[n], acc[m][n], 0, 0, 0);
    __syncthreads();
  }
  #pragma unroll
  for (int m = 0; m < 4; ++m) {
    #pragma unroll
    for (int n = 0; n < 4; ++n) {
      int gi0 = i0 + wr * 64 + m * 16 + lg * 4;
      int gj  = j0 + wc * 64 + n * 16 + lr;
      float bv = bias[gj];
      #pragma unroll
      for (int r = 0; r < 4; ++r)
        out[(size_t)(gi0 + r) * CH + gj] = acc[m][n][r] + bv;
    }
  }
}

__global__ void k_wsfail(float* out, float wsz) {
  if (threadIdx.x == 0 && blockIdx.x == 0) out[0] = wsz;
}

extern "C" void kernel_launch(void* const* d_in, const int* in_sizes, int n_in,
                              void* d_out, int out_size, void* d_ws, size_t ws_size,
                              hipStream_t stream) {
  const float* x      = (const float*)d_in[0];
  const float* w_qkv  = (const float*)d_in[1];
  const float* w_proj = (const float*)d_in[2];
  const float* b_proj = (const float*)d_in[3];
  float* out = (float*)d_out;
  char* ws = (char*)d_ws;

  const size_t QSb = (size_t)BH * NTOK * DH * sizeof(u16);    // 4 MB
  const size_t ESb = (size_t)BH * NTOK * NTOK * sizeof(u16);  // 64 MB
  const size_t CSb = (size_t)BH * NTOK * NTOK;                // 32 MB (fp8)
  const size_t need8 = ESb + 2 * CSb + 3 * QSb + (size_t)BH * NTOK * sizeof(float);  // 140.125 MB
  const size_t need9 = ESb + CSb + 3 * QSb + (size_t)BH * NTOK * sizeof(float);      // 108.125 MB

  if (ws_size >= need8) {
    // fp8-corr layout: E | E8 | Cr | q kk vT | S  (Ob/wprojb alias Cr after last fix)
    u16* E  = (u16*)(ws);
    u16* xb     = (u16*)(ws);
    u16* wqkvb  = (u16*)(ws + 4 * 1024 * 1024);
    u8*  E8 = (u8*)(ws + ESb);
    u8*  Cr = (u8*)(ws + ESb + CSb);
    u16* Ob     = (u16*)(ws + ESb + CSb);
    u16* wprojb = (u16*)(ws + ESb + CSb + 4 * 1024 * 1024);
    u16* q  = (u16*)(ws + ESb + 2 * CSb);
    u16* kk = (u16*)(ws + ESb + 2 * CSb + QSb);
    u16* vT = (u16*)(ws + ESb + 2 * CSb + 2 * QSb);
    float* S = (float*)(ws + ESb + 2 * CSb + 3 * QSb);

    hipMemsetAsync(S, 0, (size_t)BH * NTOK * sizeof(float), stream);
    k_cast<<<1024, 256, 0, stream>>>(x, xb, 262144);
    k_cast<<<384, 256, 0, stream>>>(w_qkv, wqkvb, 98304);
    k_qkv_m<<<dim3(32, 12), 256, 0, stream>>>(xb, wqkvb, q, kk, vT);
    k_qk_m<<<dim3(8, 8, BH), 256, 0, stream>>>(q, kk, E, S, E8);
    for (int it = 0; it < 3; ++it) {
      k_corr8<<<dim3(1152), 512, 0, stream>>>(E8, Cr, S, it == 0 ? 1 : 0);
      k_fix<<<dim3(BH * NTOK / 4), 256, 0, stream>>>(E, Cr, S, it < 2 ? E8 : (u8*)0,
                                                     it == 0 ? 1 : 0, it == 2 ? 1 : 0);
    }
    k_cast<<<128, 256, 0, stream>>>(w_proj, wprojb, 32768);
    k_pv_m<<<dim3(8, BH), 256, 0, stream>>>(E, vT, Ob);
    k_proj_m<<<dim3(32, 4), 256, 0, stream>>>(Ob, wprojb, b_proj, out);
  } else if (ws_size >= need9) {
    // fallback layout: E | Cr | q kk vT | S
    u16* E  = (u16*)(ws);
    u16* xb     = (u16*)(ws);
    u16* wqkvb  = (u16*)(ws + 4 * 1024 * 1024);
    u8*  Cr = (u8*)(ws + ESb);
    u16* Ob     = (u16*)(ws + ESb);
    u16* wprojb = (u16*)(ws + ESb + 4 * 1024 * 1024);
    u16* q  = (u16*)(ws + ESb + CSb);
    u16* kk = (u16*)(ws + ESb + CSb + QSb);
    u16* vT = (u16*)(ws + ESb + CSb + 2 * QSb);
    float* S = (float*)(ws + ESb + CSb + 3 * QSb);

    hipMemsetAsync(S, 0, (size_t)BH * NTOK * sizeof(float), stream);
    k_cast<<<1024, 256, 0, stream>>>(x, xb, 262144);
    k_cast<<<384, 256, 0, stream>>>(w_qkv, wqkvb, 98304);
    k_qkv_m<<<dim3(32, 12), 256, 0, stream>>>(xb, wqkvb, q, kk, vT);
    k_qk_m<<<dim3(8, 8, BH), 256, 0, stream>>>(q, kk, E, S, (u8*)0);
    for (int it = 0; it < 3; ++it) {
      k_corr<<<dim3(1152), 256, 0, stream>>>(E, Cr, S, it == 0 ? 1 : 0);
      k_fix<<<dim3(BH * NTOK / 4), 256, 0, stream>>>(E, Cr, S, (u8*)0,
                                                     it == 0 ? 1 : 0, it == 2 ? 1 : 0);
    }
    k_cast<<<128, 256, 0, stream>>>(w_proj, wprojb, 32768);
    k_pv_m<<<dim3(8, BH), 256, 0, stream>>>(E, vT, Ob);
    k_proj_m<<<dim3(32, 4), 256, 0, stream>>>(Ob, wprojb, b_proj, out);
  } else {
    k_wsfail<<<1, 64, 0, stream>>>(out, (float)ws_size);
  }
}

// Round 16
// 309.656 us; speedup vs baseline: 1.0306x; 1.0306x over previous
//
#include <hip/hip_runtime.h>
#include <hip/hip_bf16.h>
#include <math.h>

#define B_    4
#define NTOK  1024
#define CH    512
#define NH    8
#define DH    64
#define BH    32          // B_*NH
#define SCALE 0.125f      // Dh^-0.5

typedef unsigned short u16;
typedef unsigned char  u8;
typedef unsigned int   u32;
typedef short short8 __attribute__((ext_vector_type(8)));
typedef float f32x4  __attribute__((ext_vector_type(4)));
typedef float f32x2  __attribute__((ext_vector_type(2)));

#define MFMA16 __builtin_amdgcn_mfma_f32_16x16x32_bf16
#define MFMA8  __builtin_amdgcn_mfma_f32_16x16x32_fp8_fp8

__device__ __forceinline__ float b2f(u16 u) {
  union { u32 i; float f; } c; c.i = ((u32)u) << 16; return c.f;
}
__device__ __forceinline__ u16 f2b(float f) {     // round-to-nearest-even
  union { float f; u32 i; } c; c.f = f; u32 x = c.i;
  return (u16)((x + 0x7FFFu + ((x >> 16) & 1u)) >> 16);
}
__device__ __forceinline__ u8 f2fp8(float v) {
  return (u8)((u32)__builtin_amdgcn_cvt_pk_fp8_f32(v, v, 0, false) & 0xFF);
}
// pack 4 fp32 -> 4 fp8e4m3 bytes
__device__ __forceinline__ u32 pk_fp8x4(float a, float b, float c, float d) {
  u32 p = (u32)__builtin_amdgcn_cvt_pk_fp8_f32(a, b, 0, false);
  p = (u32)__builtin_amdgcn_cvt_pk_fp8_f32(c, d, (int)p, true);
  return p;
}

// async global->LDS, 16B per lane; lds addr must be linear in lane (base + lane*16)
__device__ __forceinline__ void gload16(const void* g, void* l) {
  __builtin_amdgcn_global_load_lds(
      (const __attribute__((address_space(1))) void*)g,
      (__attribute__((address_space(3))) void*)l, 16, 0, 0);
}

// ---- swizzled staging: LDS tile is [R][64B rows]. 16B slot s' holds
// global slot s'^((row>>1)&3)  ->  ds_read of (row, lg) hits 2-way max conflict.
template<int NB, int NT>
__device__ __forceinline__ void stage(const char* g, size_t gstride, char* lds) {
  #pragma unroll
  for (int off = 0; off < NB; off += NT * 16) {
    int o = off + threadIdx.x * 16;
    int row = o >> 6, slot = (o >> 4) & 3;
    gload16(g + (size_t)row * gstride + ((slot ^ ((row >> 1) & 3)) << 4), lds + o);
  }
}
__device__ __forceinline__ short8 rfrag(const char* lds, int row, int lg) {
  return *(const short8*)(lds + row * 64 + ((lg ^ ((row >> 1) & 3)) << 4));
}
// fp8 frag: row covers K=64 (two MFMA K-blocks); 8B frag at (kk, lg)
__device__ __forceinline__ long rfrag8(const u8* lds, int row, int kk, int lg) {
  return *(const long*)&lds[row * 64 + ((((kk << 1) + (lg >> 1)) ^ ((row >> 1) & 3)) << 4) + ((lg & 1) << 3)];
}

// ---------------- wave reduction helpers (64 lanes, no LDS) ----------------
__device__ __forceinline__ float wave_sum(float v) {
  #pragma unroll
  for (int o = 32; o; o >>= 1) v += __shfl_xor(v, o);
  return v;
}
__device__ __forceinline__ float wave_max(float v) {
  #pragma unroll
  for (int o = 32; o; o >>= 1) v = fmaxf(v, __shfl_xor(v, o));
  return v;
}

// ---------------- cast fp32 -> bf16, 8 elems/thread ----------------
__global__ __launch_bounds__(256) void k_cast(const float* __restrict__ a, u16* __restrict__ o, int n8) {
  int i = blockIdx.x * 256 + threadIdx.x;
  if (i >= n8) return;
  float4 v0 = ((const float4*)a)[i * 2], v1 = ((const float4*)a)[i * 2 + 1];
  ushort4 r0 = {f2b(v0.x), f2b(v0.y), f2b(v0.z), f2b(v0.w)};
  ushort4 r1 = {f2b(v1.x), f2b(v1.y), f2b(v1.z), f2b(v1.w)};
  ((ushort4*)o)[i * 2] = r0; ((ushort4*)o)[i * 2 + 1] = r1;
}

// ---------------- K1: qkv GEMM (bf16 MFMA): [4096x1536] = xb @ wb^T, scatter q/k/vT ----------------
__global__ __launch_bounds__(256) void k_qkv_m(const u16* __restrict__ xb, const u16* __restrict__ wb,
                                               u16* __restrict__ q, u16* __restrict__ kk,
                                               u16* __restrict__ vT) {
  __shared__ u16 Abuf[128 * 32], Bbuf[128 * 32];
  const int tid = threadIdx.x, w = tid >> 6, l = tid & 63;
  const int wr = w >> 1, wc = w & 1, lr = l & 15, lg = l >> 4;
  const int i0 = blockIdx.x * 128, j0 = blockIdx.y * 128;
  const char* Ax = (const char*)xb + (size_t)i0 * 1024;
  const char* Bx = (const char*)wb + (size_t)j0 * 1024;
  f32x4 acc[4][4] = {};
  for (int k0 = 0; k0 < CH; k0 += 32) {
    stage<8192, 256>(Ax + k0 * 2, 1024, (char*)Abuf);
    stage<8192, 256>(Bx + k0 * 2, 1024, (char*)Bbuf);
    __syncthreads();
    short8 a[4], b[4];
    #pragma unroll
    for (int m = 0; m < 4; ++m) a[m] = rfrag((const char*)Abuf, wr * 64 + m * 16 + lr, lg);
    #pragma unroll
    for (int n = 0; n < 4; ++n) b[n] = rfrag((const char*)Bbuf, wc * 64 + n * 16 + lr, lg);
    #pragma unroll
    for (int m = 0; m < 4; ++m)
      #pragma unroll
      for (int n = 0; n < 4; ++n)
        acc[m][n] = MFMA16(a[m], b[n], acc[m][n], 0, 0, 0);
    __syncthreads();
  }
  const int sec = j0 >> 9;          // 0=q 1=k 2=v (tile never crosses a 512 boundary)
  const int b0 = i0 >> 10;          // batch (tile never crosses a 1024 boundary)
  #pragma unroll
  for (int m = 0; m < 4; ++m) {
    #pragma unroll
    for (int n = 0; n < 4; ++n) {
      int gi0 = i0 + wr * 64 + m * 16 + lg * 4;
      int gj  = j0 + wc * 64 + n * 16 + lr;
      int h = (gj >> 6) & 7, d = gj & 63, z = b0 * 8 + h;
      if (sec == 2) {
        size_t base = ((size_t)z * 64 + d) * 1024;
        #pragma unroll
        for (int r = 0; r < 4; ++r) vT[base + ((gi0 + r) & 1023)] = f2b(acc[m][n][r]);
      } else {
        u16* dst = sec ? kk : q;
        #pragma unroll
        for (int r = 0; r < 4; ++r)
          dst[((size_t)z * 1024 + ((gi0 + r) & 1023)) * 64 + d] = f2b(acc[m][n][r]);
      }
    }
  }
}

// ---------------- K2: E = SCALE * q @ k^T per head; rowsum -> S; fp8 copy E8 ----------------
__global__ __launch_bounds__(256) void k_qk_m(const u16* __restrict__ q, const u16* __restrict__ kk,
                                              u16* __restrict__ E, float* __restrict__ S,
                                              u8* __restrict__ E8) {
  __shared__ u16 Abuf[128 * 32], Bbuf[128 * 32];
  const int z = blockIdx.z;
  const int tid = threadIdx.x, w = tid >> 6, l = tid & 63;
  const int wr = w >> 1, wc = w & 1, lr = l & 15, lg = l >> 4;
  const int i0 = blockIdx.x * 128, j0 = blockIdx.y * 128;
  const char* Ax = (const char*)(q  + (size_t)z * NTOK * DH) + (size_t)i0 * 128;
  const char* Bx = (const char*)(kk + (size_t)z * NTOK * DH) + (size_t)j0 * 128;
  u16* Eh = E + (size_t)z * NTOK * NTOK;
  u8* E8h = E8 ? E8 + (size_t)z * NTOK * NTOK : (u8*)0;
  f32x4 acc[4][4] = {};
  for (int k0 = 0; k0 < DH; k0 += 32) {
    stage<8192, 256>(Ax + k0 * 2, 128, (char*)Abuf);
    stage<8192, 256>(Bx + k0 * 2, 128, (char*)Bbuf);
    __syncthreads();
    short8 a[4], b[4];
    #pragma unroll
    for (int m = 0; m < 4; ++m) a[m] = rfrag((const char*)Abuf, wr * 64 + m * 16 + lr, lg);
    #pragma unroll
    for (int n = 0; n < 4; ++n) b[n] = rfrag((const char*)Bbuf, wc * 64 + n * 16 + lr, lg);
    #pragma unroll
    for (int m = 0; m < 4; ++m)
      #pragma unroll
      for (int n = 0; n < 4; ++n)
        acc[m][n] = MFMA16(a[m], b[n], acc[m][n], 0, 0, 0);
    __syncthreads();
  }
  #pragma unroll
  for (int m = 0; m < 4; ++m) {
    #pragma unroll
    for (int n = 0; n < 4; ++n) {
      int gi0 = i0 + wr * 64 + m * 16 + lg * 4;
      int gj  = j0 + wc * 64 + n * 16 + lr;
      #pragma unroll
      for (int r = 0; r < 4; ++r) {
        float v = SCALE * acc[m][n][r];
        Eh[(size_t)(gi0 + r) * NTOK + gj] = f2b(v);
        if (E8h) E8h[(size_t)(gi0 + r) * NTOK + gj] = f2fp8(v);
      }
    }
  }
  // rowsum partials: this wave's 64-col slice; reduce over lr (16-lane group), atomic per row
  #pragma unroll
  for (int m = 0; m < 4; ++m) {
    #pragma unroll
    for (int r = 0; r < 4; ++r) {
      float ps = SCALE * (acc[m][0][r] + acc[m][1][r] + acc[m][2][r] + acc[m][3][r]);
      #pragma unroll
      for (int o = 8; o; o >>= 1) ps += __shfl_xor(ps, o);
      if (lr == 0)
        atomicAdd(&S[(size_t)z * NTOK + i0 + wr * 64 + m * 16 + lg * 4 + r], ps);
    }
  }
}

// ---------------- K4a: corr from fp8 E8 (BK=64, fp8 16x16x32) — single-drain pipeline ----------------
__global__ __launch_bounds__(256) void k_corr8(const u8* __restrict__ E8, u8* __restrict__ Cr,
                                               const float* __restrict__ S, int first) {
  const int p = blockIdx.x;                 // 0..1151
  const int seq = p >> 3;                   // XCD head-grouping
  const int z = (p & 7) + 8 * (seq / 36);
  int t = seq % 36;
  int ti = 0;
  while (t >= 8 - ti) { t -= 8 - ti; ++ti; }
  const int tj = ti + t;
  const u8* Eh = E8 + (size_t)z * NTOK * NTOK;
  u8* Ch = Cr + (size_t)z * NTOK * NTOK;
  const int i0 = ti * 128, j0 = tj * 128;

  __shared__ u8 A8[2][8192], B8[2][8192];   // 32 KB total, [128 rows][64B = K-64 fp8]
  const int tid = threadIdx.x, w = tid >> 6, l = tid & 63;
  const int wr = w >> 1, wc = w & 1, lr = l & 15, lg = l >> 4;
  const char* Ax = (const char*)Eh + (size_t)i0 * 1024;
  const char* Bx = (const char*)Eh + (size_t)j0 * 1024;
  f32x4 acc[4][4] = {};

  stage<8192, 256>(Ax, 1024, (char*)A8[0]);
  stage<8192, 256>(Bx, 1024, (char*)B8[0]);
  int cur = 0;
  for (int k0 = 0; k0 < NTOK; k0 += 64) {
    asm volatile("s_waitcnt vmcnt(0)" ::: "memory");
    __builtin_amdgcn_s_barrier();
    asm volatile("" ::: "memory");
    long a[2][4], b[2][4];
    #pragma unroll
    for (int kk = 0; kk < 2; ++kk) {
      #pragma unroll
      for (int m = 0; m < 4; ++m) a[kk][m] = rfrag8(A8[cur], wr * 64 + m * 16 + lr, kk, lg);
      #pragma unroll
      for (int n = 0; n < 4; ++n) b[kk][n] = rfrag8(B8[cur], wc * 64 + n * 16 + lr, kk, lg);
    }
    if (k0 + 64 < NTOK) {
      stage<8192, 256>(Ax + k0 + 64, 1024, (char*)A8[cur ^ 1]);
      stage<8192, 256>(Bx + k0 + 64, 1024, (char*)B8[cur ^ 1]);
    }
    #pragma unroll
    for (int kk = 0; kk < 2; ++kk)
      #pragma unroll
      for (int m = 0; m < 4; ++m)
        #pragma unroll
        for (int n = 0; n < 4; ++n)
          acc[m][n] = MFMA8(a[kk][m], b[kk][n], acc[m][n], 0, 0, 0);
    asm volatile("" ::: "memory");
    __builtin_amdgcn_s_barrier();
    cur ^= 1;
  }

  const float c2 = 0.19f / 1024.0f;
  #pragma unroll
  for (int m = 0; m < 4; ++m) {
    #pragma unroll
    for (int n = 0; n < 4; ++n) {
      const int gi0 = i0 + wr * 64 + m * 16 + lg * 4;
      const int gj  = j0 + wc * 64 + n * 16 + lr;
      float v[4];
      if (first) {
        float sj = S[(size_t)z * NTOK + gj];
        #pragma unroll
        for (int r = 0; r < 4; ++r)
          v[r] = 0.81f * acc[m][n][r] + c2 * S[(size_t)z * NTOK + gi0 + r] * sj;
      } else {
        #pragma unroll
        for (int r = 0; r < 4; ++r) v[r] = acc[m][n][r];
      }
      #pragma unroll
      for (int r = 0; r < 4; ++r) v[r] *= 0.125f;          // 1/8 range guard
      u32 mp = pk_fp8x4(v[0], v[1], v[2], v[3]);
      #pragma unroll
      for (int r = 0; r < 4; ++r)
        Ch[(size_t)(gi0 + r) * NTOK + gj] = (u8)((mp >> (8 * r)) & 0xFF);
      if (ti != tj) {
        *(u32*)&Ch[(size_t)gj * NTOK + gi0] = mp;
      }
    }
  }
}

// ---------------- K4b: corr from bf16 E (fallback path) ----------------
__global__ __launch_bounds__(256) void k_corr(const u16* __restrict__ E, u8* __restrict__ Cr,
                                              const float* __restrict__ S, int first) {
  const int p = blockIdx.x;
  const int seq = p >> 3;
  const int z = (p & 7) + 8 * (seq / 36);
  int t = seq % 36;
  int ti = 0;
  while (t >= 8 - ti) { t -= 8 - ti; ++ti; }
  const int tj = ti + t;
  const u16* Eh = E + (size_t)z * NTOK * NTOK;
  u8* Ch = Cr + (size_t)z * NTOK * NTOK;
  const int i0 = ti * 128, j0 = tj * 128;

  __shared__ u16 Abuf[2][4096], Bbuf[2][4096];
  const int tid = threadIdx.x, w = tid >> 6, l = tid & 63;
  const int wr = w >> 1, wc = w & 1, lr = l & 15, lg = l >> 4;
  const char* Ax = (const char*)Eh + (size_t)i0 * 2048;
  const char* Bx = (const char*)Eh + (size_t)j0 * 2048;
  f32x4 acc[4][4] = {};

  stage<8192, 256>(Ax, 2048, (char*)Abuf[0]);
  stage<8192, 256>(Bx, 2048, (char*)Bbuf[0]);
  __syncthreads();
  int cur = 0;
  for (int k0 = 0; k0 < NTOK; k0 += 32) {
    if (k0 + 32 < NTOK) {
      stage<8192, 256>(Ax + (k0 + 32) * 2, 2048, (char*)Abuf[cur ^ 1]);
      stage<8192, 256>(Bx + (k0 + 32) * 2, 2048, (char*)Bbuf[cur ^ 1]);
    }
    short8 a[4], b[4];
    #pragma unroll
    for (int m = 0; m < 4; ++m) a[m] = rfrag((const char*)Abuf[cur], wr * 64 + m * 16 + lr, lg);
    #pragma unroll
    for (int n = 0; n < 4; ++n) b[n] = rfrag((const char*)Bbuf[cur], wc * 64 + n * 16 + lr, lg);
    #pragma unroll
    for (int m = 0; m < 4; ++m)
      #pragma unroll
      for (int n = 0; n < 4; ++n)
        acc[m][n] = MFMA16(a[m], b[n], acc[m][n], 0, 0, 0);
    __syncthreads();
    cur ^= 1;
  }

  const float c2 = 0.19f / 1024.0f;
  #pragma unroll
  for (int m = 0; m < 4; ++m) {
    #pragma unroll
    for (int n = 0; n < 4; ++n) {
      const int gi0 = i0 + wr * 64 + m * 16 + lg * 4;
      const int gj  = j0 + wc * 64 + n * 16 + lr;
      float v[4];
      if (first) {
        float sj = S[(size_t)z * NTOK + gj];
        #pragma unroll
        for (int r = 0; r < 4; ++r)
          v[r] = 0.81f * acc[m][n][r] + c2 * S[(size_t)z * NTOK + gi0 + r] * sj;
      } else {
        #pragma unroll
        for (int r = 0; r < 4; ++r) v[r] = acc[m][n][r];
      }
      #pragma unroll
      for (int r = 0; r < 4; ++r) v[r] *= 0.125f;
      u32 mp = pk_fp8x4(v[0], v[1], v[2], v[3]);
      #pragma unroll
      for (int r = 0; r < 4; ++r)
        Ch[(size_t)(gi0 + r) * NTOK + gj] = (u8)((mp >> (8 * r)) & 0xFF);
      if (ti != tj) {
        *(u32*)&Ch[(size_t)gj * NTOK + gi0] = mp;
      }
    }
  }
}

// ---------------- K5: E-update, wave-per-row (no LDS/barriers); optional E8 re-emit ----------------
__global__ __launch_bounds__(256) void k_fix(u16* __restrict__ E, const u8* __restrict__ Cr,
                                             const float* __restrict__ S, u8* __restrict__ E8,
                                             int fb, int last) {
  const int row = blockIdx.x * 4 + (threadIdx.x >> 6);
  const int l = threadIdx.x & 63;
  const size_t roff = (size_t)row * NTOK;

  uint4 cw = ((const uint4*)(Cr + roff))[l];          // 16 fp8
  float c[16];
  #pragma unroll
  for (int i = 0; i < 4; ++i) {
    u32 wbits = ((const u32*)&cw)[i];
    f32x2 lo = __builtin_amdgcn_cvt_pk_f32_fp8(wbits, false);
    f32x2 hi = __builtin_amdgcn_cvt_pk_f32_fp8(wbits, true);
    c[i * 4 + 0] = lo[0]; c[i * 4 + 1] = lo[1]; c[i * 4 + 2] = hi[0]; c[i * 4 + 3] = hi[1];
  }
  short8 ev0 = ((const short8*)(E + roff))[l * 2];
  short8 ev1 = ((const short8*)(E + roff))[l * 2 + 1];
  float e[16];
  #pragma unroll
  for (int i = 0; i < 8; ++i) { e[i] = b2f((u16)ev0[i]); e[8 + i] = b2f((u16)ev1[i]); }

  float ss = 0.f;
  #pragma unroll
  for (int i = 0; i < 16; ++i) ss += c[i] * c[i];
  float norm8 = sqrtf(wave_sum(ss));                  // = ||corr||/8
  float sc = 0.4f / (8.0f * norm8 + 1e-8f);           // 0.05*8

  if (fb) {
    float mm = 0.1f * S[row] * (1.0f / 1024.0f);
    #pragma unroll
    for (int i = 0; i < 16; ++i) e[i] = 0.9f * e[i] + mm;
  }
  #pragma unroll
  for (int i = 0; i < 16; ++i) e[i] += sc * c[i];

  if (!last) {
    float s = 0.f;
    #pragma unroll
    for (int i = 0; i < 16; ++i) s += e[i];
    float m = wave_sum(s) * (1.0f / 1024.0f);
    #pragma unroll
    for (int i = 0; i < 16; ++i) e[i] = 0.9f * e[i] + 0.1f * m;
    if (E8) {
      uint4 p;
      #pragma unroll
      for (int i = 0; i < 4; ++i)
        ((u32*)&p)[i] = pk_fp8x4(e[i * 4], e[i * 4 + 1], e[i * 4 + 2], e[i * 4 + 3]);
      ((uint4*)(E8 + roff))[l] = p;
    }
  } else {
    float mx = e[0];
    #pragma unroll
    for (int i = 1; i < 16; ++i) mx = fmaxf(mx, e[i]);
    mx = wave_max(mx);
    float s = 0.f;
    #pragma unroll
    for (int i = 0; i < 16; ++i) { e[i] = __expf(e[i] - mx); s += e[i]; }
    float inv = 1.0f / wave_sum(s);
    #pragma unroll
    for (int i = 0; i < 16; ++i) e[i] *= inv;
  }
  #pragma unroll
  for (int i = 0; i < 8; ++i) { ev0[i] = (short)f2b(e[i]); ev1[i] = (short)f2b(e[8 + i]); }
  ((short8*)(E + roff))[l * 2] = ev0;
  ((short8*)(E + roff))[l * 2 + 1] = ev1;
}

// ---------------- K6: Ob[4096x512] = P @ v per head (bf16 MFMA), N-tile=64 ----------------
__global__ __launch_bounds__(256) void k_pv_m(const u16* __restrict__ E, const u16* __restrict__ vT,
                                              u16* __restrict__ Ob) {
  __shared__ u16 Abuf[128 * 32], Bbuf[64 * 32];
  const int z = blockIdx.y, b0 = z >> 3, h = z & 7;
  const int tid = threadIdx.x, w = tid >> 6, l = tid & 63;
  const int wr = w >> 1, wc = w & 1, lr = l & 15, lg = l >> 4;
  const int i0 = blockIdx.x * 128;
  const char* Ax = (const char*)(E  + (size_t)z * NTOK * NTOK) + (size_t)i0 * 2048;
  const char* Bx = (const char*)(vT + (size_t)z * DH * NTOK);
  f32x4 acc[4][2] = {};
  for (int k0 = 0; k0 < NTOK; k0 += 32) {
    stage<8192, 256>(Ax + k0 * 2, 2048, (char*)Abuf);
    stage<4096, 256>(Bx + k0 * 2, 2048, (char*)Bbuf);
    __syncthreads();
    short8 a[4], b[2];
    #pragma unroll
    for (int m = 0; m < 4; ++m) a[m] = rfrag((const char*)Abuf, wr * 64 + m * 16 + lr, lg);
    #pragma unroll
    for (int n = 0; n < 2; ++n) b[n] = rfrag((const char*)Bbuf, wc * 32 + n * 16 + lr, lg);
    #pragma unroll
    for (int m = 0; m < 4; ++m)
      #pragma unroll
      for (int n = 0; n < 2; ++n)
        acc[m][n] = MFMA16(a[m], b[n], acc[m][n], 0, 0, 0);
    __syncthreads();
  }
  #pragma unroll
  for (int m = 0; m < 4; ++m) {
    #pragma unroll
    for (int n = 0; n < 2; ++n) {
      int gi0 = i0 + wr * 64 + m * 16 + lg * 4;
      int d   = wc * 32 + n * 16 + lr;
      #pragma unroll
      for (int r = 0; r < 4; ++r)
        Ob[((size_t)b0 * 1024 + gi0 + r) * 512 + h * 64 + d] = f2b(acc[m][n][r]);
    }
  }
}

// ---------------- K7: out[4096x512] = Ob @ wprojb^T + bias (bf16 MFMA, fp32 out) ----------------
__global__ __launch_bounds__(256) void k_proj_m(const u16* __restrict__ Ob, const u16* __restrict__ wb,
                                                const float* __restrict__ bias, float* __restrict__ out) {
  __shared__ u16 Abuf[128 * 32], Bbuf[128 * 32];
  const int tid = threadIdx.x, w = tid >> 6, l = tid & 63;
  const int wr = w >> 1, wc = w & 1, lr = l & 15, lg = l >> 4;
  const int i0 = blockIdx.x * 128, j0 = blockIdx.y * 128;
  const char* Ax = (const char*)Ob + (size_t)i0 * 1024;
  const char* Bx = (const char*)wb + (size_t)j0 * 1024;
  f32x4 acc[4][4] = {};
  for (int k0 = 0; k0 < CH; k0 += 32) {
    stage<8192, 256>(Ax + k0 * 2, 1024, (char*)Abuf);
    stage<8192, 256>(Bx + k0 * 2, 1024, (char*)Bbuf);
    __syncthreads();
    short8 a[4], b[4];
    #pragma unroll
    for (int m = 0; m < 4; ++m) a[m] = rfrag((const char*)Abuf, wr * 64 + m * 16 + lr, lg);
    #pragma unroll
    for (int n = 0; n < 4; ++n) b[n] = rfrag((const char*)Bbuf, wc * 64 + n * 16 + lr, lg);
    #pragma unroll
    for (int m = 0; m < 4; ++m)
      #pragma unroll
      for (int n = 0; n < 4; ++n)
        acc[m][n] = MFMA16(a[m], b[n], acc[m][n], 0, 0, 0);
    __syncthreads();
  }
  #pragma unroll
  for (int m = 0; m < 4; ++m) {
    #pragma unroll
    for (int n = 0; n < 4; ++n) {
      int gi0 = i0 + wr * 64 + m * 16 + lg * 4;
      int gj  = j0 + wc * 64 + n * 16 + lr;
      float bv = bias[gj];
      #pragma unroll
      for (int r = 0; r < 4; ++r)
        out[(size_t)(gi0 + r) * CH + gj] = acc[m][n][r] + bv;
    }
  }
}

__global__ void k_wsfail(float* out, float wsz) {
  if (threadIdx.x == 0 && blockIdx.x == 0) out[0] = wsz;
}

extern "C" void kernel_launch(void* const* d_in, const int* in_sizes, int n_in,
                              void* d_out, int out_size, void* d_ws, size_t ws_size,
                              hipStream_t stream) {
  const float* x      = (const float*)d_in[0];
  const float* w_qkv  = (const float*)d_in[1];
  const float* w_proj = (const float*)d_in[2];
  const float* b_proj = (const float*)d_in[3];
  float* out = (float*)d_out;
  char* ws = (char*)d_ws;

  const size_t QSb = (size_t)BH * NTOK * DH * sizeof(u16);    // 4 MB
  const size_t ESb = (size_t)BH * NTOK * NTOK * sizeof(u16);  // 64 MB
  const size_t CSb = (size_t)BH * NTOK * NTOK;                // 32 MB (fp8)
  const size_t need8 = ESb + 2 * CSb + 3 * QSb + (size_t)BH * NTOK * sizeof(float);  // 140.125 MB
  const size_t need9 = ESb + CSb + 3 * QSb + (size_t)BH * NTOK * sizeof(float);      // 108.125 MB

  if (ws_size >= need8) {
    // fp8-corr layout: E | E8 | Cr | q kk vT | S  (Ob/wprojb alias Cr after last fix)
    u16* E  = (u16*)(ws);
    u16* xb     = (u16*)(ws);
    u16* wqkvb  = (u16*)(ws + 4 * 1024 * 1024);
    u8*  E8 = (u8*)(ws + ESb);
    u8*  Cr = (u8*)(ws + ESb + CSb);
    u16* Ob     = (u16*)(ws + ESb + CSb);
    u16* wprojb = (u16*)(ws + ESb + CSb + 4 * 1024 * 1024);
    u16* q  = (u16*)(ws + ESb + 2 * CSb);
    u16* kk = (u16*)(ws + ESb + 2 * CSb + QSb);
    u16* vT = (u16*)(ws + ESb + 2 * CSb + 2 * QSb);
    float* S = (float*)(ws + ESb + 2 * CSb + 3 * QSb);

    hipMemsetAsync(S, 0, (size_t)BH * NTOK * sizeof(float), stream);
    k_cast<<<1024, 256, 0, stream>>>(x, xb, 262144);
    k_cast<<<384, 256, 0, stream>>>(w_qkv, wqkvb, 98304);
    k_qkv_m<<<dim3(32, 12), 256, 0, stream>>>(xb, wqkvb, q, kk, vT);
    k_qk_m<<<dim3(8, 8, BH), 256, 0, stream>>>(q, kk, E, S, E8);
    for (int it = 0; it < 3; ++it) {
      k_corr8<<<dim3(1152), 256, 0, stream>>>(E8, Cr, S, it == 0 ? 1 : 0);
      k_fix<<<dim3(BH * NTOK / 4), 256, 0, stream>>>(E, Cr, S, it < 2 ? E8 : (u8*)0,
                                                     it == 0 ? 1 : 0, it == 2 ? 1 : 0);
    }
    k_cast<<<128, 256, 0, stream>>>(w_proj, wprojb, 32768);
    k_pv_m<<<dim3(8, BH), 256, 0, stream>>>(E, vT, Ob);
    k_proj_m<<<dim3(32, 4), 256, 0, stream>>>(Ob, wprojb, b_proj, out);
  } else if (ws_size >= need9) {
    // fallback layout: E | Cr | q kk vT | S
    u16* E  = (u16*)(ws);
    u16* xb     = (u16*)(ws);
    u16* wqkvb  = (u16*)(ws + 4 * 1024 * 1024);
    u8*  Cr = (u8*)(ws + ESb);
    u16* Ob     = (u16*)(ws + ESb);
    u16* wprojb = (u16*)(ws + ESb + 4 * 1024 * 1024);
    u16* q  = (u16*)(ws + ESb + CSb);
    u16* kk = (u16*)(ws + ESb + CSb + QSb);
    u16* vT = (u16*)(ws + ESb + CSb + 2 * QSb);
    float* S = (float*)(ws + ESb + CSb + 3 * QSb);

    hipMemsetAsync(S, 0, (size_t)BH * NTOK * sizeof(float), stream);
    k_cast<<<1024, 256, 0, stream>>>(x, xb, 262144);
    k_cast<<<384, 256, 0, stream>>>(w_qkv, wqkvb, 98304);
    k_qkv_m<<<dim3(32, 12), 256, 0, stream>>>(xb, wqkvb, q, kk, vT);
    k_qk_m<<<dim3(8, 8, BH), 256, 0, stream>>>(q, kk, E, S, (u8*)0);
    for (int it = 0; it < 3; ++it) {
      k_corr<<<dim3(1152), 256, 0, stream>>>(E, Cr, S, it == 0 ? 1 : 0);
      k_fix<<<dim3(BH * NTOK / 4), 256, 0, stream>>>(E, Cr, S, (u8*)0,
                                                     it == 0 ? 1 : 0, it == 2 ? 1 : 0);
    }
    k_cast<<<128, 256, 0, stream>>>(w_proj, wprojb, 32768);
    k_pv_m<<<dim3(8, BH), 256, 0, stream>>>(E, vT, Ob);
    k_proj_m<<<dim3(32, 4), 256, 0, stream>>>(Ob, wprojb, b_proj, out);
  } else {
    k_wsfail<<<1, 64, 0, stream>>>(out, (float)ws_size);
  }
}